// Round 7
// baseline (114.324 us; speedup 1.0000x reference)
//
#include <hip/hip_runtime.h>
#include <hip/hip_bf16.h>

#define NN_ 8192
#define DD_ 128
#define NCLS 512
#define NSPLIT 32
#define JSPLIT (NN_ / NSPLIT)  // 256

typedef short bf16x8 __attribute__((ext_vector_type(8)));
typedef float f32x4 __attribute__((ext_vector_type(4)));

union U4 { uint4 u; bf16x8 h; };

#if __has_builtin(__builtin_amdgcn_exp2f)
#define EXP2(x) __builtin_amdgcn_exp2f(x)
#else
#define EXP2(x) __expf((x) * 0.69314718056f)
#endif

#define C1 115.415603f  /* 80*log2(e); NOTE 0.16*C1 + C2 == C1 exactly */
#define C2 96.9491065f  /* 67.2*log2(e) */
#define LN2 0.69314718056f

__device__ __forceinline__ unsigned short f2bf(float f) {
    unsigned int u = __float_as_uint(f);
    unsigned int r = (u + 0x7FFFu + ((u >> 16) & 1u)) >> 16;  // RNE
    return (unsigned short)r;
}

// Fragment-swizzled layout (uint4 units): fb[grp*256 + chunk*16 + row16]
//   grp = slot>>4, row16 = slot&15, chunk = 8-bf16 block (16B) in [0,16).
// MFMA frag load for K-block kc reads fb[grp*256 + kc*64 + lane]; each
// 16-col group is 4KB contiguous -> a 64-col tile is one 16KB memcpy.
// Rows label-sorted; same-label cols of a wave's 32 rows are one range
// [lo, hi); subtiles outside it use the 5-op negative path.
//
// R7 diagnosis: R1/R4/R5/R6 all ~37-43us with every pipe <50% busy ->
// latency-bound (per-32col-iter: prefetch not covered by ~300cyc compute,
// vmcnt(0)+barrier every iter). Fix: 64-col tiles (4x compute per iter,
// ~800cyc covers L2/L3 latency; 5 barriers/block), NSPLIT=32 restores
// 1024 blocks, and exp-arg algebra: C1*max(s+.4,0)*(s-.4)-C2 ==
// C1*(max(s,-.4)^2-1) -> 5 VALU/element on the hot path.

// ---------------- sort pipeline (parallel counting sort) ------------------------
// No runtime API calls in kernel_launch (graph capture). [R3 lesson]
__global__ __launch_bounds__(512) void k_zero(int* __restrict__ hist) {
    hist[threadIdx.x] = 0;
}

__global__ __launch_bounds__(256) void k_hist(const int* __restrict__ labels,
                                              int* __restrict__ hist) {
    int i = blockIdx.x * 256 + threadIdx.x;
    atomicAdd(&hist[labels[i]], 1);
}

// 1 block, 512 threads: exclusive scan hist -> start (and base copy).
__global__ __launch_bounds__(512) void k_scan(const int* __restrict__ hist,
                                              int* __restrict__ start,
                                              int* __restrict__ base) {
    __shared__ int wsum[8];
    int t = threadIdx.x;
    int v = hist[t];
    int x = v;
#pragma unroll
    for (int m = 1; m < 64; m <<= 1) {
        int y = __shfl_up(x, m);
        if ((t & 63) >= m) x += y;
    }
    if ((t & 63) == 63) wsum[t >> 6] = x;
    __syncthreads();
    int w = t >> 6, woff = 0;
#pragma unroll
    for (int k = 0; k < 8; k++)
        if (k < w) woff += wsum[k];
    int excl = woff + x - v;  // exclusive prefix over classes
    start[t] = excl;
    base[t] = excl;
    if (t == 0) start[NCLS] = NN_;
}

__global__ __launch_bounds__(256) void k_scatter(const int* __restrict__ labels,
                                                 int* __restrict__ base,
                                                 int* __restrict__ srcrow,
                                                 int* __restrict__ plab) {
    int row = blockIdx.x * 256 + threadIdx.x;
    int l = labels[row];
    int p = atomicAdd(&base[l], 1);
    srcrow[p] = row;
    plab[p] = l;
}

// ---------------- kernel 1: L2-normalize rows -> bf16 (gather, coalesced store) -
__global__ __launch_bounds__(256) void k_norm(const float* __restrict__ x,
                                              const int* __restrict__ srcrow,
                                              unsigned short* __restrict__ ebf) {
    int t = threadIdx.x;
    int r16 = t >> 4;
    int g = t & 15;
    int slot = blockIdx.x * 16 + r16;
    int orig = srcrow[slot];  // 16 threads/row load same value (cache broadcast)
    const float4* xr = (const float4*)(x + (size_t)orig * DD_);
    float4 v0 = xr[g * 2];
    float4 v1 = xr[g * 2 + 1];
    float ss = v0.x * v0.x + v0.y * v0.y + v0.z * v0.z + v0.w * v0.w +
               v1.x * v1.x + v1.y * v1.y + v1.z * v1.z + v1.w * v1.w;
#pragma unroll
    for (int m = 1; m < 16; m <<= 1) ss += __shfl_xor(ss, m);
    float inv = 1.0f / fmaxf(sqrtf(ss), 1e-12f);
    float vs[8] = {v0.x, v0.y, v0.z, v0.w, v1.x, v1.y, v1.z, v1.w};
    unsigned int p[4];
#pragma unroll
    for (int k = 0; k < 4; k++) {
        unsigned short lo = f2bf(vs[2 * k] * inv);
        unsigned short hi = f2bf(vs[2 * k + 1] * inv);
        p[k] = (unsigned int)lo | ((unsigned int)hi << 16);
    }
    uint4 out = {p[0], p[1], p[2], p[3]};
    ((uint4*)ebf)[blockIdx.x * 256 + g * 16 + r16] = out;  // coalesced swizzled store
}

// ---------------- kernel 2: main sim + masked LSE pass --------------------------
// grid (NSPLIT=32, 32) = 1024 blocks, 512 threads (8 waves), 32 rows/wave.
// 64-col tiles double-buffered in LDS (2x16KB); prefetch issued at iteration
// top, ds_write after ~800cyc of compute, one barrier per 64 cols.
// launch_bounds min-waves 4 (128-VGPR cap): 8 caused scratch spills. [R2]
__global__ __launch_bounds__(512, 4) void k_main(const unsigned short* __restrict__ ebf,
                                                 const int* __restrict__ plab,
                                                 const int* __restrict__ start,
                                                 float* __restrict__ states) {
    __shared__ uint4 bsh[2048];  // 2 buffers x 1024 uint4 (16KB each)

    const int tid = threadIdx.x;
    const int lane = tid & 63;
    const int wave = tid >> 6;
    const int quad = lane >> 4;
    const int lcol = lane & 15;
    const int rowbase = blockIdx.y * 256 + wave * 32;
    const int jsplit = blockIdx.x;
    const int j0 = jsplit * JSPLIT;

    const uint4* fb = (const uint4*)ebf;

    // two A-fragment sets: rows rowbase..+15 (g=0) and rowbase+16..+31 (g=1)
    U4 afr[2][4];
#pragma unroll
    for (int g = 0; g < 2; g++)
#pragma unroll
        for (int kc = 0; kc < 4; kc++)
            afr[g][kc].u = fb[((rowbase >> 4) + g) * 256 + kc * 64 + lane];

    int il[2][4];
#pragma unroll
    for (int g = 0; g < 2; g++)
#pragma unroll
        for (int r = 0; r < 4; r++) il[g][r] = plab[rowbase + g * 16 + quad * 4 + r];

    // wave-uniform same-label column range [lo, hi) over all 32 rows
    int labmin = __builtin_amdgcn_readfirstlane(plab[rowbase]);
    int labmax = __builtin_amdgcn_readfirstlane(plab[rowbase + 31]);
    int lo = __builtin_amdgcn_readfirstlane(start[labmin]);
    int hi = __builtin_amdgcn_readfirstlane(start[labmax + 1]);

    float S_an[2][4], m_p[2][4], s_p[2][4], cnt[2][4];
#pragma unroll
    for (int g = 0; g < 2; g++)
#pragma unroll
        for (int r = 0; r < 4; r++) {
            S_an[g][r] = 0.f;
            m_p[g][r] = -1e30f;  // log2 units
            s_p[g][r] = 0.f;
            cnt[g][r] = 0.f;
        }

    // prologue: stage tile 0 (cols j0..j0+63, 16KB contiguous) into buffer 0
    {
        const int tb = (j0 >> 4) * 256;
        bsh[tid] = fb[tb + tid];
        bsh[tid + 512] = fb[tb + tid + 512];
    }
    __syncthreads();

    const int NIT = JSPLIT / 64;  // 4
    for (int it = 0; it < NIT; ++it) {
        const int cur = it & 1;
        const int jt = j0 + it * 64;
        const bool has = (it + 1 < NIT);

        // prefetch next 64-col tile NOW; vmcnt(0) lands after the 4-subtile
        // compute below (~800cyc of issue) -> latency covered
        uint4 stg0, stg1;
        if (has) {
            const int tn = ((jt + 64) >> 4) * 256;
            stg0 = fb[tn + tid];
            stg1 = fb[tn + tid + 512];
        }

        const int bbase = (cur << 10) + lane;

        // ---- four 16-col subtiles from LDS buffer `cur` ----
#pragma unroll
        for (int c = 0; c < 4; c++) {
            U4 bf[4];
#pragma unroll
            for (int kc = 0; kc < 4; kc++) bf[kc].u = bsh[bbase + c * 256 + kc * 64];
            f32x4 acc0 = {0.f, 0.f, 0.f, 0.f};
            f32x4 acc1 = {0.f, 0.f, 0.f, 0.f};
#pragma unroll
            for (int kc = 0; kc < 4; kc++) {
                acc0 = __builtin_amdgcn_mfma_f32_16x16x32_bf16(afr[0][kc].h, bf[kc].h, acc0, 0, 0, 0);
                acc1 = __builtin_amdgcn_mfma_f32_16x16x32_bf16(afr[1][kc].h, bf[kc].h, acc1, 0, 0, 0);
            }
            const int jc = jt + c * 16;
            if (jc < hi && jc + 16 > lo) {
                int jl = plab[jc + lcol];
                int j = jc + lcol;
#pragma unroll
                for (int g = 0; g < 2; g++) {
#pragma unroll
                    for (int r = 0; r < 4; r++) {
                        float s = (g == 0) ? acc0[r] : acc1[r];
                        int i = rowbase + g * 16 + quad * 4 + r;
                        bool same = (jl == il[g][r]);
                        float u = fmaxf(s, -0.4f);
                        float e = EXP2(fmaf(u * C1, u, -C1));
                        S_an[g][r] += same ? 0.0f : e;
                        cnt[g][r] += same ? 1.0f : 0.0f;
                        if (same && j != i) {
                            float al = fmaxf(1.4f - s, 0.0f) * (-C1);
                            float tp = al * (s - 0.6f);
                            float mn = fmaxf(m_p[g][r], tp);
                            s_p[g][r] = s_p[g][r] * EXP2(m_p[g][r] - mn) + EXP2(tp - mn);
                            m_p[g][r] = mn;
                        }
                    }
                }
            } else {
                // pure negative: e = exp2(C1*(max(s,-0.4)^2 - 1)), 5 ops/elem
#pragma unroll
                for (int r = 0; r < 4; r++) {
                    float u0 = fmaxf(acc0[r], -0.4f);
                    S_an[0][r] += EXP2(fmaf(u0 * C1, u0, -C1));
                    float u1 = fmaxf(acc1[r], -0.4f);
                    S_an[1][r] += EXP2(fmaf(u1 * C1, u1, -C1));
                }
            }
        }

        // late half of the stage: write next tile into the other buffer.
        // Reads of that buffer finished before the PREVIOUS barrier -> safe.
        if (has) {
            bsh[((cur ^ 1) << 10) + tid] = stg0;
            bsh[((cur ^ 1) << 10) + tid + 512] = stg1;
        }
        __syncthreads();
    }

#pragma unroll
    for (int g = 0; g < 2; g++)
#pragma unroll
        for (int r = 0; r < 4; r++) {
#pragma unroll
            for (int m = 1; m < 16; m <<= 1) {
                S_an[g][r] += __shfl_xor(S_an[g][r], m);
                cnt[g][r] += __shfl_xor(cnt[g][r], m);
                float m2 = __shfl_xor(m_p[g][r], m);
                float s2 = __shfl_xor(s_p[g][r], m);
                float mn = fmaxf(m_p[g][r], m2);
                s_p[g][r] = s_p[g][r] * EXP2(m_p[g][r] - mn) + s2 * EXP2(m2 - mn);
                m_p[g][r] = mn;
            }
        }
    if (lcol == 0) {
#pragma unroll
        for (int g = 0; g < 2; g++)
#pragma unroll
            for (int r = 0; r < 4; r++) {
                int i = rowbase + g * 16 + quad * 4 + r;
                float4 st = {m_p[g][r], s_p[g][r], S_an[g][r], cnt[g][r]};
                ((float4*)states)[(size_t)i * NSPLIT + jsplit] = st;
            }
    }
}

// ---------------- kernel 3: merge splits, per-row loss, per-wave partials -------
__global__ __launch_bounds__(256) void k_fin(const float* __restrict__ states,
                                             float* __restrict__ partials) {
    int i = blockIdx.x * 256 + threadIdx.x;
    float m_p = -1e30f, s_p = 0.f, S_an = 0.f, cnt = 0.f;
#pragma unroll
    for (int k = 0; k < NSPLIT; k++) {
        float4 st = ((const float4*)states)[(size_t)i * NSPLIT + k];
        S_an += st.z;
        cnt += st.w;
        float mn = fmaxf(m_p, st.x);
        s_p = s_p * EXP2(m_p - mn) + st.y * EXP2(st.x - mn);
        m_p = mn;
    }
    int np = (int)cnt - 1;
    int nn = NN_ - (int)cnt;
    float loss = 0.0f, v = 0.0f;
    if (np > 0 && nn > 0 && s_p > 0.f && S_an > 0.f) {
        float lse_p = LN2 * m_p + __logf(s_p);
        float lse_n = 67.2f + __logf(S_an);
        float z = lse_p + lse_n + __logf((float)np) + __logf((float)nn);
        loss = fmaxf(z, 0.0f) + log1pf(__expf(-fabsf(z)));  // stable softplus
        v = 1.0f;
    }
#pragma unroll
    for (int m = 1; m < 64; m <<= 1) {
        loss += __shfl_xor(loss, m);
        v += __shfl_xor(v, m);
    }
    if ((threadIdx.x & 63) == 0) {
        int w = (blockIdx.x << 2) | (threadIdx.x >> 6);
        partials[w * 2] = loss;
        partials[w * 2 + 1] = v;
    }
}

// ---------------- kernel 4: final reduce over 128 wave-partials -----------------
__global__ void k_div(const float* __restrict__ partials, float* __restrict__ out) {
    int t = threadIdx.x;  // 64 threads
    float loss = partials[t * 2] + partials[(t + 64) * 2];
    float v = partials[t * 2 + 1] + partials[(t + 64) * 2 + 1];
#pragma unroll
    for (int m = 1; m < 64; m <<= 1) {
        loss += __shfl_xor(loss, m);
        v += __shfl_xor(v, m);
    }
    if (t == 0) out[0] = loss / fmaxf(v, 1.0f);
}

// ---------------- launch --------------------------------------------------------
extern "C" void kernel_launch(void* const* d_in, const int* in_sizes, int n_in,
                              void* d_out, int out_size, void* d_ws, size_t ws_size,
                              hipStream_t stream) {
    const float* embeds = (const float*)d_in[0];
    const int* labels = (const int*)d_in[1];
    float* out = (float*)d_out;

    char* ws = (char*)d_ws;
    unsigned short* ebf = (unsigned short*)ws;  // 2,097,152 B
    float* states = (float*)(ws + 2097152);     // 8192*32*16 = 4,194,304 B
    float* partials = (float*)(ws + 6291456);   // 1,024 B
    int* srcrow = (int*)(ws + 6292480);         // 32,768 B
    int* plab = (int*)(ws + 6325248);           // 32,768 B
    int* start = (int*)(ws + 6358016);          // 2,052 B (513 ints)
    int* base = (int*)(ws + 6360068);           // 2,048 B
    int* hist = (int*)(ws + 6362116);           // 2,048 B

    k_zero<<<1, NCLS, 0, stream>>>(hist);
    k_hist<<<NN_ / 256, 256, 0, stream>>>(labels, hist);
    k_scan<<<1, NCLS, 0, stream>>>(hist, start, base);
    k_scatter<<<NN_ / 256, 256, 0, stream>>>(labels, base, srcrow, plab);
    k_norm<<<NN_ / 16, 256, 0, stream>>>(embeds, srcrow, ebf);
    k_main<<<dim3(NSPLIT, NN_ / 256), 512, 0, stream>>>(ebf, plab, start, states);
    k_fin<<<NN_ / 256, 256, 0, stream>>>(states, partials);
    k_div<<<1, 64, 0, stream>>>(partials, out);
}

// Round 8
// 109.053 us; speedup vs baseline: 1.0483x; 1.0483x over previous
//
#include <hip/hip_runtime.h>
#include <hip/hip_bf16.h>

#define NN_ 8192
#define DD_ 128
#define NCLS 512
#define NSPLIT 32
#define JSPLIT (NN_ / NSPLIT)  // 256

typedef short bf16x8 __attribute__((ext_vector_type(8)));
typedef float f32x4 __attribute__((ext_vector_type(4)));

union U4 { uint4 u; bf16x8 h; };

#if __has_builtin(__builtin_amdgcn_exp2f)
#define EXP2(x) __builtin_amdgcn_exp2f(x)
#else
#define EXP2(x) __expf((x) * 0.69314718056f)
#endif

#define C1 115.415603f  /* 80*log2(e); NOTE 0.16*C1 + C2 == C1 exactly */
#define C2 96.9491065f  /* 67.2*log2(e) */
#define LN2 0.69314718056f

__device__ __forceinline__ unsigned short f2bf(float f) {
    unsigned int u = __float_as_uint(f);
    unsigned int r = (u + 0x7FFFu + ((u >> 16) & 1u)) >> 16;  // RNE
    return (unsigned short)r;
}

// Fragment-swizzled layout (uint4 units): fb[grp*256 + chunk*16 + row16]
//   grp = slot>>4, row16 = slot&15, chunk = 8-bf16 block (16B) in [0,16).
// MFMA frag load for K-block kc reads fb[grp*256 + kc*64 + lane]; each
// 16-col group is 4KB contiguous -> a 64-col tile is one 16KB memcpy.
// Rows label-sorted; same-label cols of a wave's 32 rows are one range
// [lo, hi); subtiles outside it use the 5-op negative path.
//
// R8 diagnosis: R1..R7 all ~41-44us regardless of traffic/latency structure.
// Issue-slot accounting: 22k VALU wave-instr/SIMD = 21/element-group vs ~5
// designed -> ISSUE-COUNT bound. Diet: (a) Z-register MFMA C-in kills 32
// zero-movs/subtile (~20% of VALU); (b) cnt accumulator deleted (class size
// = start[l+1]-start[l] after sort); (c) zero+hist+scan fused to 1 launch.

// ---------------- sort pipeline (parallel counting sort) ------------------------
// No runtime API calls in kernel_launch (graph capture). [R3 lesson]
// 1 block, 1024 threads: LDS hist + LDS scan -> start/base. [R8: fused]
__global__ __launch_bounds__(1024) void k_sorthead(const int* __restrict__ labels,
                                                   int* __restrict__ start,
                                                   int* __restrict__ base) {
    __shared__ int hist[NCLS];
    __shared__ int wsum[8];
    int t = threadIdx.x;
    if (t < NCLS) hist[t] = 0;
    __syncthreads();
    int4 la = ((const int4*)labels)[t * 2];
    int4 lb = ((const int4*)labels)[t * 2 + 1];
    atomicAdd(&hist[la.x], 1);
    atomicAdd(&hist[la.y], 1);
    atomicAdd(&hist[la.z], 1);
    atomicAdd(&hist[la.w], 1);
    atomicAdd(&hist[lb.x], 1);
    atomicAdd(&hist[lb.y], 1);
    atomicAdd(&hist[lb.z], 1);
    atomicAdd(&hist[lb.w], 1);
    __syncthreads();
    int v = (t < NCLS) ? hist[t] : 0;
    int x = v;
#pragma unroll
    for (int m = 1; m < 64; m <<= 1) {
        int y = __shfl_up(x, m);
        if ((t & 63) >= m) x += y;
    }
    if (t < NCLS && (t & 63) == 63) wsum[t >> 6] = x;
    __syncthreads();
    if (t < NCLS) {
        int w = t >> 6, woff = 0;
#pragma unroll
        for (int k = 0; k < 8; k++)
            if (k < w) woff += wsum[k];
        int excl = woff + x - v;  // exclusive prefix over classes
        start[t] = excl;
        base[t] = excl;
        if (t == 0) start[NCLS] = NN_;
    }
}

__global__ __launch_bounds__(256) void k_scatter(const int* __restrict__ labels,
                                                 int* __restrict__ base,
                                                 int* __restrict__ srcrow,
                                                 int* __restrict__ plab) {
    int row = blockIdx.x * 256 + threadIdx.x;
    int l = labels[row];
    int p = atomicAdd(&base[l], 1);
    srcrow[p] = row;
    plab[p] = l;
}

// ---------------- kernel 1: L2-normalize rows -> bf16 (gather, coalesced store) -
__global__ __launch_bounds__(256) void k_norm(const float* __restrict__ x,
                                              const int* __restrict__ srcrow,
                                              unsigned short* __restrict__ ebf) {
    int t = threadIdx.x;
    int r16 = t >> 4;
    int g = t & 15;
    int slot = blockIdx.x * 16 + r16;
    int orig = srcrow[slot];  // 16 threads/row load same value (cache broadcast)
    const float4* xr = (const float4*)(x + (size_t)orig * DD_);
    float4 v0 = xr[g * 2];
    float4 v1 = xr[g * 2 + 1];
    float ss = v0.x * v0.x + v0.y * v0.y + v0.z * v0.z + v0.w * v0.w +
               v1.x * v1.x + v1.y * v1.y + v1.z * v1.z + v1.w * v1.w;
#pragma unroll
    for (int m = 1; m < 16; m <<= 1) ss += __shfl_xor(ss, m);
    float inv = 1.0f / fmaxf(sqrtf(ss), 1e-12f);
    float vs[8] = {v0.x, v0.y, v0.z, v0.w, v1.x, v1.y, v1.z, v1.w};
    unsigned int p[4];
#pragma unroll
    for (int k = 0; k < 4; k++) {
        unsigned short lo = f2bf(vs[2 * k] * inv);
        unsigned short hi = f2bf(vs[2 * k + 1] * inv);
        p[k] = (unsigned int)lo | ((unsigned int)hi << 16);
    }
    uint4 out = {p[0], p[1], p[2], p[3]};
    ((uint4*)ebf)[blockIdx.x * 256 + g * 16 + r16] = out;  // coalesced swizzled store
}

// ---------------- kernel 2: main sim + masked LSE pass --------------------------
// grid (NSPLIT=32, 32) = 1024 blocks, 512 threads (8 waves), 32 rows/wave.
// 64-col tiles double-buffered in LDS (2x16KB); one barrier per 64 cols.
// launch_bounds min-waves 4 (128-VGPR cap): 8 caused scratch spills. [R2]
__global__ __launch_bounds__(512, 4) void k_main(const unsigned short* __restrict__ ebf,
                                                 const int* __restrict__ plab,
                                                 const int* __restrict__ start,
                                                 float* __restrict__ states) {
    __shared__ uint4 bsh[2048];  // 2 buffers x 1024 uint4 (16KB each)

    const int tid = threadIdx.x;
    const int lane = tid & 63;
    const int wave = tid >> 6;
    const int quad = lane >> 4;
    const int lcol = lane & 15;
    const int rowbase = blockIdx.y * 256 + wave * 32;
    const int jsplit = blockIdx.x;
    const int j0 = jsplit * JSPLIT;

    const uint4* fb = (const uint4*)ebf;

    // two A-fragment sets: rows rowbase..+15 (g=0) and rowbase+16..+31 (g=1)
    U4 afr[2][4];
#pragma unroll
    for (int g = 0; g < 2; g++)
#pragma unroll
        for (int kc = 0; kc < 4; kc++)
            afr[g][kc].u = fb[((rowbase >> 4) + g) * 256 + kc * 64 + lane];

    int il[2][4];
#pragma unroll
    for (int g = 0; g < 2; g++)
#pragma unroll
        for (int r = 0; r < 4; r++) il[g][r] = plab[rowbase + g * 16 + quad * 4 + r];

    // wave-uniform same-label column range [lo, hi) over all 32 rows
    int labmin = __builtin_amdgcn_readfirstlane(plab[rowbase]);
    int labmax = __builtin_amdgcn_readfirstlane(plab[rowbase + 31]);
    int lo = __builtin_amdgcn_readfirstlane(start[labmin]);
    int hi = __builtin_amdgcn_readfirstlane(start[labmax + 1]);

    float S_an[2][4], m_p[2][4], s_p[2][4];
#pragma unroll
    for (int g = 0; g < 2; g++)
#pragma unroll
        for (int r = 0; r < 4; r++) {
            S_an[g][r] = 0.f;
            m_p[g][r] = -1e30f;  // log2 units
            s_p[g][r] = 0.f;
        }

    const f32x4 Z = {0.f, 0.f, 0.f, 0.f};  // shared C-in: no per-subtile zero-init

    // prologue: stage tile 0 (cols j0..j0+63, 16KB contiguous) into buffer 0
    {
        const int tb = (j0 >> 4) * 256;
        bsh[tid] = fb[tb + tid];
        bsh[tid + 512] = fb[tb + tid + 512];
    }
    __syncthreads();

    const int NIT = JSPLIT / 64;  // 4
    for (int it = 0; it < NIT; ++it) {
        const int cur = it & 1;
        const int jt = j0 + it * 64;
        const bool has = (it + 1 < NIT);

        // prefetch next 64-col tile NOW; latency covered by 4-subtile compute
        uint4 stg0, stg1;
        if (has) {
            const int tn = ((jt + 64) >> 4) * 256;
            stg0 = fb[tn + tid];
            stg1 = fb[tn + tid + 512];
        }

        const int bbase = (cur << 10) + lane;

        // ---- four 16-col subtiles from LDS buffer `cur` ----
#pragma unroll
        for (int c = 0; c < 4; c++) {
            U4 bf[4];
#pragma unroll
            for (int kc = 0; kc < 4; kc++) bf[kc].u = bsh[bbase + c * 256 + kc * 64];
            f32x4 acc0 = __builtin_amdgcn_mfma_f32_16x16x32_bf16(afr[0][0].h, bf[0].h, Z, 0, 0, 0);
            f32x4 acc1 = __builtin_amdgcn_mfma_f32_16x16x32_bf16(afr[1][0].h, bf[0].h, Z, 0, 0, 0);
#pragma unroll
            for (int kc = 1; kc < 4; kc++) {
                acc0 = __builtin_amdgcn_mfma_f32_16x16x32_bf16(afr[0][kc].h, bf[kc].h, acc0, 0, 0, 0);
                acc1 = __builtin_amdgcn_mfma_f32_16x16x32_bf16(afr[1][kc].h, bf[kc].h, acc1, 0, 0, 0);
            }
            const int jc = jt + c * 16;
            if (jc < hi && jc + 16 > lo) {
                int jl = plab[jc + lcol];
                int j = jc + lcol;
#pragma unroll
                for (int g = 0; g < 2; g++) {
#pragma unroll
                    for (int r = 0; r < 4; r++) {
                        float s = (g == 0) ? acc0[r] : acc1[r];
                        int i = rowbase + g * 16 + quad * 4 + r;
                        bool same = (jl == il[g][r]);
                        float u = fmaxf(s, -0.4f);
                        float e = EXP2(fmaf(u * C1, u, -C1));
                        S_an[g][r] += same ? 0.0f : e;
                        if (same && j != i) {
                            float al = fmaxf(1.4f - s, 0.0f) * (-C1);
                            float tp = al * (s - 0.6f);
                            float mn = fmaxf(m_p[g][r], tp);
                            s_p[g][r] = s_p[g][r] * EXP2(m_p[g][r] - mn) + EXP2(tp - mn);
                            m_p[g][r] = mn;
                        }
                    }
                }
            } else {
                // pure negative: e = exp2(C1*(max(s,-0.4)^2 - 1)), 5 ops/elem
#pragma unroll
                for (int r = 0; r < 4; r++) {
                    float u0 = fmaxf(acc0[r], -0.4f);
                    S_an[0][r] += EXP2(fmaf(u0 * C1, u0, -C1));
                    float u1 = fmaxf(acc1[r], -0.4f);
                    S_an[1][r] += EXP2(fmaf(u1 * C1, u1, -C1));
                }
            }
        }

        // late half of the stage: write next tile into the other buffer.
        if (has) {
            bsh[((cur ^ 1) << 10) + tid] = stg0;
            bsh[((cur ^ 1) << 10) + tid + 512] = stg1;
        }
        __syncthreads();
    }

#pragma unroll
    for (int g = 0; g < 2; g++)
#pragma unroll
        for (int r = 0; r < 4; r++) {
#pragma unroll
            for (int m = 1; m < 16; m <<= 1) {
                S_an[g][r] += __shfl_xor(S_an[g][r], m);
                float m2 = __shfl_xor(m_p[g][r], m);
                float s2 = __shfl_xor(s_p[g][r], m);
                float mn = fmaxf(m_p[g][r], m2);
                s_p[g][r] = s_p[g][r] * EXP2(m_p[g][r] - mn) + s2 * EXP2(m2 - mn);
                m_p[g][r] = mn;
            }
        }
    if (lcol == 0) {
#pragma unroll
        for (int g = 0; g < 2; g++)
#pragma unroll
            for (int r = 0; r < 4; r++) {
                int i = rowbase + g * 16 + quad * 4 + r;
                float4 st = {m_p[g][r], s_p[g][r], S_an[g][r], 0.f};
                ((float4*)states)[(size_t)i * NSPLIT + jsplit] = st;
            }
    }
}

// ---------------- kernel 3: merge splits, per-row loss, per-wave partials -------
// np/nn from class size via plab/start (cnt accumulator deleted). [R8]
__global__ __launch_bounds__(256) void k_fin(const float* __restrict__ states,
                                             const int* __restrict__ plab,
                                             const int* __restrict__ start,
                                             float* __restrict__ partials) {
    int i = blockIdx.x * 256 + threadIdx.x;
    float m_p = -1e30f, s_p = 0.f, S_an = 0.f;
#pragma unroll
    for (int k = 0; k < NSPLIT; k++) {
        float4 st = ((const float4*)states)[(size_t)i * NSPLIT + k];
        S_an += st.z;
        float mn = fmaxf(m_p, st.x);
        s_p = s_p * EXP2(m_p - mn) + st.y * EXP2(st.x - mn);
        m_p = mn;
    }
    int l = plab[i];
    int sz = start[l + 1] - start[l];  // class size (incl self)
    int np = sz - 1;
    int nn = NN_ - sz;
    float loss = 0.0f, v = 0.0f;
    if (np > 0 && nn > 0 && s_p > 0.f && S_an > 0.f) {
        float lse_p = LN2 * m_p + __logf(s_p);
        float lse_n = 67.2f + __logf(S_an);
        float z = lse_p + lse_n + __logf((float)np) + __logf((float)nn);
        loss = fmaxf(z, 0.0f) + log1pf(__expf(-fabsf(z)));  // stable softplus
        v = 1.0f;
    }
#pragma unroll
    for (int m = 1; m < 64; m <<= 1) {
        loss += __shfl_xor(loss, m);
        v += __shfl_xor(v, m);
    }
    if ((threadIdx.x & 63) == 0) {
        int w = (blockIdx.x << 2) | (threadIdx.x >> 6);
        partials[w * 2] = loss;
        partials[w * 2 + 1] = v;
    }
}

// ---------------- kernel 4: final reduce over 128 wave-partials -----------------
__global__ void k_div(const float* __restrict__ partials, float* __restrict__ out) {
    int t = threadIdx.x;  // 64 threads
    float loss = partials[t * 2] + partials[(t + 64) * 2];
    float v = partials[t * 2 + 1] + partials[(t + 64) * 2 + 1];
#pragma unroll
    for (int m = 1; m < 64; m <<= 1) {
        loss += __shfl_xor(loss, m);
        v += __shfl_xor(v, m);
    }
    if (t == 0) out[0] = loss / fmaxf(v, 1.0f);
}

// ---------------- launch --------------------------------------------------------
extern "C" void kernel_launch(void* const* d_in, const int* in_sizes, int n_in,
                              void* d_out, int out_size, void* d_ws, size_t ws_size,
                              hipStream_t stream) {
    const float* embeds = (const float*)d_in[0];
    const int* labels = (const int*)d_in[1];
    float* out = (float*)d_out;

    char* ws = (char*)d_ws;
    unsigned short* ebf = (unsigned short*)ws;  // 2,097,152 B
    float* states = (float*)(ws + 2097152);     // 8192*32*16 = 4,194,304 B
    float* partials = (float*)(ws + 6291456);   // 1,024 B
    int* srcrow = (int*)(ws + 6292480);         // 32,768 B
    int* plab = (int*)(ws + 6325248);           // 32,768 B
    int* start = (int*)(ws + 6358016);          // 2,052 B (513 ints)
    int* base = (int*)(ws + 6360068);           // 2,048 B

    k_sorthead<<<1, 1024, 0, stream>>>(labels, start, base);
    k_scatter<<<NN_ / 256, 256, 0, stream>>>(labels, base, srcrow, plab);
    k_norm<<<NN_ / 16, 256, 0, stream>>>(embeds, srcrow, ebf);
    k_main<<<dim3(NSPLIT, NN_ / 256), 512, 0, stream>>>(ebf, plab, start, states);
    k_fin<<<NN_ / 256, 256, 0, stream>>>(states, plab, start, partials);
    k_div<<<1, 64, 0, stream>>>(partials, out);
}